// Round 4
// baseline (113.444 us; speedup 1.0000x reference)
//
#include <hip/hip_runtime.h>
#include <hip/hip_bf16.h>

typedef __hip_bfloat16 bf16;
typedef short bf16x8 __attribute__((ext_vector_type(8)));
typedef float f32x4 __attribute__((ext_vector_type(4)));

#define S_LEN 4096
#define NBATCH 2
#define EDIM 1024
#define DDIM 64
#define MROWS (NBATCH * S_LEN)   // 8192

union frag_u { bf16x8 v; bf16 e[8]; };

// f32x8 -> split bf16 hi/lo fragments (x ~= hi + lo, rel err ~2^-17)
__device__ __forceinline__ void cvt_split(const float4& a, const float4& b,
                                          bf16x8& hi, bf16x8& lo) {
  float v[8] = {a.x, a.y, a.z, a.w, b.x, b.y, b.z, b.w};
  frag_u h, l;
#pragma unroll
  for (int e = 0; e < 8; e++) {
    bf16 hh = __float2bfloat16(v[e]);
    h.e[e] = hh;
    l.e[e] = __float2bfloat16(v[e] - __bfloat162float(hh));
  }
  hi = h.v;
  lo = l.v;
}

// ---------------------------------------------------------------------------
// Pack weights (f32, k-major [1024][64]) -> split-bf16 in ROUND-MAJOR
// order: Wt2[j=0..31][unit u=0..767][8 bf16], round j covers k in
// [j*32, j*32+32). Unit for (n, kk): n2 = n>>1, pp = (n&1)*4 + (kk>>3),
// sp = pp ^ (n2 & 7), u = n2*8 + sp, elem = kk&7. A round block = 12288 B.
// The gemm reads lane units DIRECTLY from global (each (nt, round) is a
// contiguous, fully-consumed 1 KB segment -> perfect coalescing, L2-hot).
// Grid 48 = 3 mats x 16 k-blocks. Block 0 zeroes Vsum.
// ---------------------------------------------------------------------------
__global__ __launch_bounds__(256) void pack_w_kernel(
    const float* __restrict__ Wq, const float* __restrict__ Wk,
    const float* __restrict__ Wv, bf16* __restrict__ Wt2_hi,
    bf16* __restrict__ Wt2_lo, float* __restrict__ Vsum) {
  __shared__ float tile[64 * 65];
  const int mat = blockIdx.x >> 4;
  const int kb = blockIdx.x & 15;             // 64-k block -> rounds 2kb,2kb+1
  const int t = threadIdx.x;
  if (blockIdx.x == 0 && t < NBATCH * DDIM) Vsum[t] = 0.f;
  const float* W = (mat == 0) ? Wq : ((mat == 1) ? Wk : Wv);

#pragma unroll
  for (int i = 0; i < 4; i++) {
    int F = (i * 256 + t) * 4;                // flat f32 idx in [0,4096)
    int k = F >> 6;
    int n4 = F & 63;
    float4 v = *(const float4*)(const void*)(W + (size_t)(kb * 64 + k) * 64 + n4);
    tile[(n4 + 0) * 65 + k] = v.x;
    tile[(n4 + 1) * 65 + k] = v.y;
    tile[(n4 + 2) * 65 + k] = v.z;
    tile[(n4 + 3) * 65 + k] = v.w;
  }
  __syncthreads();

  // 512 units (hi+lo written together): nl, j_half, pp_k
#pragma unroll
  for (int it = 0; it < 2; it++) {
    int uidx = it * 256 + t;
    int nl = uidx >> 3;
    int j_half = (uidx >> 2) & 1;
    int pp_k = uidx & 3;
    int ng = mat * 64 + nl;                   // global n in [0,192)
    int n2 = ng >> 1;
    int sp = ((ng & 1) * 4 + pp_k) ^ (n2 & 7);
    int unit = n2 * 8 + sp;
    int j = kb * 2 + j_half;
    frag_u h, l;
#pragma unroll
    for (int e = 0; e < 8; e++) {
      float v = tile[nl * 65 + j_half * 32 + pp_k * 8 + e];
      bf16 hh = __float2bfloat16(v);
      h.e[e] = hh;
      l.e[e] = __float2bfloat16(v - __bfloat162float(hh));
    }
    size_t ob = (size_t)j * 6144 + unit * 8;
    *(bf16x8*)(void*)(Wt2_hi + ob) = h.v;
    *(bf16x8*)(void*)(Wt2_lo + ob) = l.v;
  }
}

// ---------------------------------------------------------------------------
// Fused QKV GEMM v9 — all-register with ENGINEERED QUEUE SLACK.
// v8 post-mortem: three structures all ~35-45us at <12% pipe busy =>
// achieved x-BW ~1 TB/s => only ~5-10 KB A-reads in flight per CU
// (Little's law). Cause: in-order vmcnt retirement — consuming B(r) with
// 1-round slack retired OLDER A(r+1)/A(r+2) HBM loads, collapsing A's
// slack; rings too shallow besides.
// v9 rule: all issues at ROUND END, B before A. Queue order per round r:
//   ... B(r+3), A(r+5) ...  =>  waiting on B(r) retires nothing newer than
// B(r) (all A issued after it); waiting on A(r) has 5-round slack; B(r)
// has 3-round slack. No barriers, no LDS in the loop, no inline waits —
// compiler dependency waitcnts + issue ORDER give the pipeline.
// Rings: A 5 slots (80 VGPR), B 3 slots (72), acc 24, ~210 total
// => 2 waves/SIMD. In-flight A per CU > 100 KB => x at HBM rate.
// Shape: 8 waves = nh(0..3) x kh(0..1), 32 rows/block, grid 256 (1/CU),
// 16 rounds/wave, 18 MFMA/round; LDS only for the kh-merge epilogue.
// MFMA f32_16x16x32_bf16 split-bf16 (xh*wh + xh*wl + xl*wh):
//   A[m][k]: m=lane&15, k=(lane>>4)*8+e | B[k][n]: n=lane&15, k=(lane>>4)*8+e
//   D[m][n]: m=(lane>>4)*4+r, n=lane&15
// ---------------------------------------------------------------------------
__global__ __launch_bounds__(512, 2) void qkv_gemm_kernel(
    const float* __restrict__ x, const bf16* __restrict__ Wt2_hi,
    const bf16* __restrict__ Wt2_lo, const float* __restrict__ bq,
    const float* __restrict__ bk, const float* __restrict__ bv,
    float* __restrict__ qkv, float* __restrict__ Vsum) {
  __shared__ f32x4 red[4][64][6];             // 24.5 KB, epilogue merge only
  const int tid = threadIdx.x;
  const int lane = tid & 63;
  const int wave = tid >> 6;                  // 0..7
  const int nh = wave & 3;                    // n-group (3 n-tiles)
  const int kh = wave >> 2;                   // k-half
  const int quad = lane >> 4;
  const int l16 = lane & 15;
  const int rowBase = blockIdx.x * 32;

  // B lane pointer (pre-swizzled pack layout): unit = nt*512 + loff bf16
  const int sp = ((l16 & 1) * 4 + quad) ^ ((l16 >> 1) & 7);
  const int loff = ((l16 >> 1) * 8 + sp) * 8;
  const bf16* bhp = Wt2_hi + (size_t)kh * 98304 + nh * 1536 + loff;  // 16*6144
  const bf16* blp = Wt2_lo + (size_t)kh * 98304 + nh * 1536 + loff;

  // A lane pointers: mfrag f row = rowBase + f*16 + l16, byte off =
  // kh*2048 + quad*32 + r*128
  const char* aB0 = (const char*)x + (size_t)(rowBase + l16) * 4096 +
                    kh * 2048 + quad * 32;
  const char* aB1 = aB0 + 16 * 4096;

  float4 Ab[5][2][2];                         // [slot][mfrag][half]
  bf16x8 Bh[3][3], Bl[3][3];                  // [slot][t]
  f32x4 acc[2][3];
#pragma unroll
  for (int f = 0; f < 2; f++)
#pragma unroll
    for (int t = 0; t < 3; t++) acc[f][t] = (f32x4){0.f, 0.f, 0.f, 0.f};

#define LOADB(s, r)                                                          \
  {                                                                          \
    const bf16* _h = bhp + (size_t)(r) * 6144;                               \
    const bf16* _l = blp + (size_t)(r) * 6144;                               \
    Bh[s][0] = *(const bf16x8*)(const void*)(_h);                            \
    Bh[s][1] = *(const bf16x8*)(const void*)(_h + 512);                      \
    Bh[s][2] = *(const bf16x8*)(const void*)(_h + 1024);                     \
    Bl[s][0] = *(const bf16x8*)(const void*)(_l);                            \
    Bl[s][1] = *(const bf16x8*)(const void*)(_l + 512);                      \
    Bl[s][2] = *(const bf16x8*)(const void*)(_l + 1024);                     \
  }
#define LOADA(s, r)                                                          \
  {                                                                          \
    Ab[s][0][0] = *(const float4*)(const void*)(aB0 + (r) * 128);            \
    Ab[s][0][1] = *(const float4*)(const void*)(aB0 + (r) * 128 + 16);       \
    Ab[s][1][0] = *(const float4*)(const void*)(aB1 + (r) * 128);            \
    Ab[s][1][1] = *(const float4*)(const void*)(aB1 + (r) * 128 + 16);       \
  }

  // prologue: B rounds 0-2 (ring 3), A rounds 0-4 (ring 5), interleaved
  LOADB(0, 0);
  LOADA(0, 0);
  LOADB(1, 1);
  LOADA(1, 1);
  LOADB(2, 2);
  LOADA(2, 2);
  LOADA(3, 3);
  LOADA(4, 4);
  asm volatile("" ::: "memory");

#pragma unroll
  for (int r = 0; r < 16; ++r) {
    // consume round r (waits: A(r) 5-round slack, B(r) 3-round slack;
    // neither retires any younger unconsumed load — see header comment)
    bf16x8 ah0, al0, ah1, al1;
    cvt_split(Ab[r % 5][0][0], Ab[r % 5][0][1], ah0, al0);
    cvt_split(Ab[r % 5][1][0], Ab[r % 5][1][1], ah1, al1);
    const int s = r % 3;
#pragma unroll
    for (int t = 0; t < 3; t++) {
      acc[0][t] =
          __builtin_amdgcn_mfma_f32_16x16x32_bf16(ah0, Bh[s][t], acc[0][t], 0, 0, 0);
      acc[0][t] =
          __builtin_amdgcn_mfma_f32_16x16x32_bf16(ah0, Bl[s][t], acc[0][t], 0, 0, 0);
      acc[0][t] =
          __builtin_amdgcn_mfma_f32_16x16x32_bf16(al0, Bh[s][t], acc[0][t], 0, 0, 0);
      acc[1][t] =
          __builtin_amdgcn_mfma_f32_16x16x32_bf16(ah1, Bh[s][t], acc[1][t], 0, 0, 0);
      acc[1][t] =
          __builtin_amdgcn_mfma_f32_16x16x32_bf16(ah1, Bl[s][t], acc[1][t], 0, 0, 0);
      acc[1][t] =
          __builtin_amdgcn_mfma_f32_16x16x32_bf16(al1, Bh[s][t], acc[1][t], 0, 0, 0);
    }
    // issues at ROUND END, B before A (keeps B-waits decoupled from A)
    if (r + 3 < 16) LOADB((r + 3) % 3, r + 3);
    if (r + 5 < 16) LOADA((r + 5) % 5, r + 5);
    asm volatile("" ::: "memory");            // pin issues in this round
  }
#undef LOADA
#undef LOADB

  // merge k-halves: waves 4-7 export, waves 0-3 absorb
  if (kh == 1) {
#pragma unroll
    for (int f = 0; f < 2; f++)
#pragma unroll
      for (int t = 0; t < 3; t++) red[nh][lane][f * 3 + t] = acc[f][t];
  }
  __syncthreads();
  if (kh == 1) return;
#pragma unroll
  for (int f = 0; f < 2; f++)
#pragma unroll
    for (int t = 0; t < 3; t++) acc[f][t] += red[nh][lane][f * 3 + t];

  // epilogue: bias + store + V column sums
  const int bb = rowBase >> 12;
#pragma unroll
  for (int f = 0; f < 2; f++)
#pragma unroll
    for (int t = 0; t < 3; t++) {
      int nt = nh * 3 + t;
      int n = nt * 16 + l16;
      int mat = n >> 6;
      int col = n & 63;
      float bias = (mat == 0) ? bq[col] : ((mat == 1) ? bk[col] : bv[col]);
      float* dst = qkv + (size_t)mat * MROWS * DDIM +
                   (size_t)(rowBase + f * 16 + quad * 4) * DDIM + col;
      float vs = 0.f;
#pragma unroll
      for (int rr = 0; rr < 4; rr++) {
        float val = acc[f][t][rr] + bias;
        dst[rr * DDIM] = val;
        vs += val;
      }
      if (nt >= 8) {                          // V tiles -> Vsum
        vs += __shfl_xor(vs, 16, 64);
        vs += __shfl_xor(vs, 32, 64);
        if (quad == 0) atomicAdd(&Vsum[bb * DDIM + (n - 128)], vs);
      }
    }
}

// ---------------------------------------------------------------------------
// Attention: 2 queries per wave, 32 lanes each, lane owns a float2 dim-pair.
// Full-row softmax collapses to: 5 window exps + (S - nvalid) background
// exp(0-m) terms; background numerator = Vsum - sum(window V).
// ---------------------------------------------------------------------------
__global__ __launch_bounds__(256) void attn_kernel(
    const float* __restrict__ qkv, const float* __restrict__ Vsum,
    float* __restrict__ out) {
  const float* Qf = qkv;
  const float* Kf = qkv + (size_t)MROWS * DDIM;
  const float* Vf = qkv + (size_t)2 * MROWS * DDIM;
  int l = threadIdx.x & 31;
  int qidx = blockIdx.x * 8 + (threadIdx.x >> 5);
  int b = qidx >> 12;
  int i = qidx & 4095;

  float2 q = *(const float2*)(const void*)(Qf + (size_t)qidx * DDIM + 2 * l);
  float sc[5];
  float2 vv[5];
  bool val[5];
#pragma unroll
  for (int w = 0; w < 5; w++) {
    int j = i + 2 * w - 4;                    // DIL*(w - WIN/2), DIL=2
    val[w] = (j >= 0) && (j < S_LEN);
    int jj = val[w] ? j : i;
    size_t off = (size_t)(b * S_LEN + jj) * DDIM + 2 * l;
    float2 kk = *(const float2*)(const void*)(Kf + off);
    vv[w] = *(const float2*)(const void*)(Vf + off);
    float p = q.x * kk.x + q.y * kk.y;
#pragma unroll
    for (int d = 1; d < 32; d <<= 1) p += __shfl_xor(p, d, 64);
    sc[w] = p;
  }

  float mx = 0.f;                             // background score 0 in the max
#pragma unroll
  for (int w = 0; w < 5; w++)
    if (val[w]) mx = fmaxf(mx, sc[w]);

  float denom = 0.f;
  float2 accv = {0.f, 0.f}, vsel = {0.f, 0.f};
  int nval = 0;
#pragma unroll
  for (int w = 0; w < 5; w++)
    if (val[w]) {
      float pexp = __expf(sc[w] - mx);
      denom += pexp;
      accv.x += pexp * vv[w].x;
      accv.y += pexp * vv[w].y;
      vsel.x += vv[w].x;
      vsel.y += vv[w].y;
      nval++;
    }
  float pbg = __expf(-mx);
  denom += pbg * (float)(S_LEN - nval);
  float2 vsm = *(const float2*)(const void*)(Vsum + b * DDIM + 2 * l);
  accv.x += pbg * (vsm.x - vsel.x);
  accv.y += pbg * (vsm.y - vsel.y);

  float2 o = {accv.x / denom, accv.y / denom};
  *(float2*)(void*)(out + (size_t)qidx * DDIM + 2 * l) = o;
}

// ---------------------------------------------------------------------------
extern "C" void kernel_launch(void* const* d_in, const int* in_sizes, int n_in,
                              void* d_out, int out_size, void* d_ws,
                              size_t ws_size, hipStream_t stream) {
  const float* x = (const float*)d_in[0];
  const float* Wq = (const float*)d_in[1];
  const float* bq = (const float*)d_in[2];
  const float* Wk = (const float*)d_in[3];
  const float* bk = (const float*)d_in[4];
  const float* Wv = (const float*)d_in[5];
  const float* bv = (const float*)d_in[6];
  float* out = (float*)d_out;

  char* ws = (char*)d_ws;
  bf16* Wt2_hi = (bf16*)ws;                   // 32*6144*2 = 393216 B
  bf16* Wt2_lo = (bf16*)(ws + 393216);        // 393216 B
  float* qkv = (float*)(ws + 786432);         // 3*8192*64*4 = 6291456 B
  float* Vsum = (float*)(ws + 786432 + 6291456);  // 512 B
  // total workspace ~7.1 MB

  hipLaunchKernelGGL(pack_w_kernel, dim3(48), dim3(256), 0, stream, Wq, Wk, Wv,
                     Wt2_hi, Wt2_lo, Vsum);
  hipLaunchKernelGGL(qkv_gemm_kernel, dim3(256), dim3(512), 0, stream, x,
                     Wt2_hi, Wt2_lo, bq, bk, bv, qkv, Vsum);
  hipLaunchKernelGGL(attn_kernel, dim3(1024), dim3(256), 0, stream, qkv, Vsum,
                     out);
}

// Round 5
// 106.378 us; speedup vs baseline: 1.0664x; 1.0664x over previous
//
#include <hip/hip_runtime.h>
#include <hip/hip_bf16.h>

typedef __hip_bfloat16 bf16;
typedef short bf16x8 __attribute__((ext_vector_type(8)));
typedef float f32x4 __attribute__((ext_vector_type(4)));

#define S_LEN 4096
#define NBATCH 2
#define EDIM 1024
#define DDIM 64
#define MROWS (NBATCH * S_LEN)   // 8192

#define GLOBAL_AS __attribute__((address_space(1)))
#define LDS_AS __attribute__((address_space(3)))

union frag_u { bf16x8 v; bf16 e[8]; };

// async 16B global -> LDS (dest wave-uniform; HW adds lane*16; src per-lane)
__device__ __forceinline__ void async_ld16(const void* gp, void* lp) {
  __builtin_amdgcn_global_load_lds((const GLOBAL_AS void*)gp,
                                   (LDS_AS void*)lp, 16, 0, 0);
}

// f32x8 -> split bf16 hi/lo fragments (x ~= hi + lo, rel err ~2^-17)
__device__ __forceinline__ void cvt_split(const float4& a, const float4& b,
                                          bf16x8& hi, bf16x8& lo) {
  float v[8] = {a.x, a.y, a.z, a.w, b.x, b.y, b.z, b.w};
  frag_u h, l;
#pragma unroll
  for (int e = 0; e < 8; e++) {
    bf16 hh = __float2bfloat16(v[e]);
    h.e[e] = hh;
    l.e[e] = __float2bfloat16(v[e] - __bfloat162float(hh));
  }
  hi = h.v;
  lo = l.v;
}

// ---------------------------------------------------------------------------
// Pack weights (f32, k-major [1024][64]) -> split-bf16 in ROUND-MAJOR
// order: Wt2[j=0..31][unit u=0..767][8 bf16], round j covers k in
// [j*32, j*32+32). Unit for (n, kk): n2 = n>>1, pp = (n&1)*4 + (kk>>3),
// sp = pp ^ (n2 & 7), u = n2*8 + sp, elem = kk&7. A round block = 12288 B.
// The gemm reads lane units DIRECTLY from global (each (nt, round) is a
// contiguous, fully-consumed 1 KB segment -> perfect coalescing, L2-hot).
// Grid 48 = 3 mats x 16 k-blocks. Block 0 zeroes Vsum.
// ---------------------------------------------------------------------------
__global__ __launch_bounds__(256) void pack_w_kernel(
    const float* __restrict__ Wq, const float* __restrict__ Wk,
    const float* __restrict__ Wv, bf16* __restrict__ Wt2_hi,
    bf16* __restrict__ Wt2_lo, float* __restrict__ Vsum) {
  __shared__ float tile[64 * 65];
  const int mat = blockIdx.x >> 4;
  const int kb = blockIdx.x & 15;             // 64-k block -> rounds 2kb,2kb+1
  const int t = threadIdx.x;
  if (blockIdx.x == 0 && t < NBATCH * DDIM) Vsum[t] = 0.f;
  const float* W = (mat == 0) ? Wq : ((mat == 1) ? Wk : Wv);

#pragma unroll
  for (int i = 0; i < 4; i++) {
    int F = (i * 256 + t) * 4;                // flat f32 idx in [0,4096)
    int k = F >> 6;
    int n4 = F & 63;
    float4 v = *(const float4*)(const void*)(W + (size_t)(kb * 64 + k) * 64 + n4);
    tile[(n4 + 0) * 65 + k] = v.x;
    tile[(n4 + 1) * 65 + k] = v.y;
    tile[(n4 + 2) * 65 + k] = v.z;
    tile[(n4 + 3) * 65 + k] = v.w;
  }
  __syncthreads();

  // 512 units (hi+lo written together): nl, j_half, pp_k
#pragma unroll
  for (int it = 0; it < 2; it++) {
    int uidx = it * 256 + t;
    int nl = uidx >> 3;
    int j_half = (uidx >> 2) & 1;
    int pp_k = uidx & 3;
    int ng = mat * 64 + nl;                   // global n in [0,192)
    int n2 = ng >> 1;
    int sp = ((ng & 1) * 4 + pp_k) ^ (n2 & 7);
    int unit = n2 * 8 + sp;
    int j = kb * 2 + j_half;
    frag_u h, l;
#pragma unroll
    for (int e = 0; e < 8; e++) {
      float v = tile[nl * 65 + j_half * 32 + pp_k * 8 + e];
      bf16 hh = __float2bfloat16(v);
      h.e[e] = hh;
      l.e[e] = __float2bfloat16(v - __bfloat162float(hh));
    }
    size_t ob = (size_t)j * 6144 + unit * 8;
    *(bf16x8*)(void*)(Wt2_hi + ob) = h.v;
    *(bf16x8*)(void*)(Wt2_lo + ob) = l.v;
  }
}

// ---------------------------------------------------------------------------
// Fused QKV GEMM v10 — CONTIGUOUS-BURST A staging.
// v9 post-mortem: v8==v9 exactly => in-flight depth was never the limit.
// Invariant across ALL slow versions: every A-access instruction gathered
// 8-16 rows of x at 4 KB stride (row stride = 4096 B) — 16 scattered 64-B
// segments per instruction, power-of-2 stride aliasing the channel hash =>
// ~1 TB/s cap regardless of queue depth.
// v10: stage the block's WHOLE A panel (32 rows x 4 KB = 128 KB) into LDS
// up-front with 128 global_load_lds instructions, EACH a 1-KB contiguous
// burst of ONE row. Per-lane source swizzle (lane ^ (row&7) on low-3 chunk
// bits) pre-applies the LDS bank swizzle while keeping the burst contiguous
// (same address set, permuted lanes). One vmcnt(18) + one s_barrier, then a
// BARRIER-FREE, DMA-FREE K-loop: B register loads only (L2-hot, ring-3,
// issued at round end), swizzled ds_read_b128 A-fragments (2-way = free),
// 18 MFMA/round. kh-merge reuses the A-LDS after a sync.
// Shape: 8 waves = nh(0..3) x kh(0..1), 32 rows/block, grid 256 (1 blk/CU,
// 2 waves/SIMD), 16 rounds/wave. MFMA-issue floor/SIMD: 2w x 16r x 18 x
// 19.4cyc ~= 11.2k cyc ~= 4.7 us.
// A-frag read: row = f*16 + l16, chunk c = Rk*8 + quad*2 + s; LDS addr =
// row*4096 + (c ^ (row&7))*16; per-8-lane phase covers all 8 bank groups.
// MFMA f32_16x16x32_bf16 split-bf16 (xh*wh + xh*wl + xl*wh):
//   A[m][k]: m=lane&15, k=(lane>>4)*8+e | B[k][n]: n=lane&15, k=(lane>>4)*8+e
//   D[m][n]: m=(lane>>4)*4+r, n=lane&15
// ---------------------------------------------------------------------------
__global__ __launch_bounds__(512, 2) void qkv_gemm_kernel(
    const float* __restrict__ x, const bf16* __restrict__ Wt2_hi,
    const bf16* __restrict__ Wt2_lo, const float* __restrict__ bq,
    const float* __restrict__ bk, const float* __restrict__ bv,
    float* __restrict__ qkv, float* __restrict__ Vsum) {
  __shared__ __align__(16) char lds[131072];  // 32 rows x 4096 B (A panel)
  const int tid = threadIdx.x;
  const int lane = tid & 63;
  const int wave = tid >> 6;                  // 0..7
  const int nh = wave & 3;                    // n-group (3 n-tiles)
  const int kh = wave >> 2;                   // k-half
  const int quad = lane >> 4;
  const int l16 = lane & 15;
  const int rowBase = blockIdx.x * 32;

  // B lane pointer (pre-swizzled pack layout): unit = nt*512 + loff bf16
  const int sp = ((l16 & 1) * 4 + quad) ^ ((l16 >> 1) & 7);
  const int loff = ((l16 >> 1) * 8 + sp) * 8;
  const bf16* bhp = Wt2_hi + (size_t)kh * 98304 + nh * 1536 + loff;  // 16*6144
  const bf16* blp = Wt2_lo + (size_t)kh * 98304 + nh * 1536 + loff;

  bf16x8 Bh[3][3], Bl[3][3];                  // [slot][t]
  f32x4 acc[2][3];
#pragma unroll
  for (int f = 0; f < 2; f++)
#pragma unroll
    for (int t = 0; t < 3; t++) acc[f][t] = (f32x4){0.f, 0.f, 0.f, 0.f};

#define LOADB(s, r)                                                          \
  {                                                                          \
    const bf16* _h = bhp + (size_t)(r) * 6144;                               \
    const bf16* _l = blp + (size_t)(r) * 6144;                               \
    Bh[s][0] = *(const bf16x8*)(const void*)(_h);                            \
    Bh[s][1] = *(const bf16x8*)(const void*)(_h + 512);                      \
    Bh[s][2] = *(const bf16x8*)(const void*)(_h + 1024);                     \
    Bl[s][0] = *(const bf16x8*)(const void*)(_l);                            \
    Bl[s][1] = *(const bf16x8*)(const void*)(_l + 512);                      \
    Bl[s][2] = *(const bf16x8*)(const void*)(_l + 1024);                     \
  }

  // ---- stage ALL of A: wave w -> rows w*4..w*4+3, 4x 1-KB bursts per row.
  // Each DMA: 64 lanes x 16 B contiguous from ONE row; lane->chunk XOR
  // pre-swizzle (low-3 bits) = LDS image LDS[R][c] = x[R][c ^ (R&7)].
#pragma unroll
  for (int i = 0; i < 16; i++) {
    const int Rl = (wave << 2) | (i >> 2);
    const int g = i & 3;
    const char* src = (const char*)x + (size_t)(rowBase + Rl) * 4096 +
                      (size_t)g * 1024 + ((lane ^ (Rl & 7)) << 4);
    async_ld16(src, lds + Rl * 4096 + g * 1024);
  }
  asm volatile("" ::: "memory");              // DMAs strictly before B loads
  LOADB(0, 0);
  LOADB(1, 1);
  LOADB(2, 2);
  // own 16 DMAs retired (18 B loads may remain in flight); then cross-wave
  asm volatile("s_waitcnt vmcnt(18)" ::: "memory");
  __builtin_amdgcn_s_barrier();
  __builtin_amdgcn_sched_barrier(0);

  // A fragment bases: rows l16 and 16+l16 ((16+l16)&7 == l16&7)
  const char* aRow0 = lds + l16 * 4096;
  const char* aRow1 = lds + (16 + l16) * 4096;
  const int aE = (((quad * 2) ^ (l16 & 7)) << 4);

#pragma unroll
  for (int r = 0; r < 16; ++r) {
    const int Rk = kh * 16 + r;               // absolute K-round
    float4 a00 = *(const float4*)(const void*)(aRow0 + Rk * 128 + aE);
    float4 a01 = *(const float4*)(const void*)(aRow0 + Rk * 128 + (aE ^ 16));
    float4 a10 = *(const float4*)(const void*)(aRow1 + Rk * 128 + aE);
    float4 a11 = *(const float4*)(const void*)(aRow1 + Rk * 128 + (aE ^ 16));
    bf16x8 ah0, al0, ah1, al1;
    cvt_split(a00, a01, ah0, al0);
    cvt_split(a10, a11, ah1, al1);
    const int s = r % 3;
#pragma unroll
    for (int t = 0; t < 3; t++) {
      acc[0][t] =
          __builtin_amdgcn_mfma_f32_16x16x32_bf16(ah0, Bh[s][t], acc[0][t], 0, 0, 0);
      acc[0][t] =
          __builtin_amdgcn_mfma_f32_16x16x32_bf16(ah0, Bl[s][t], acc[0][t], 0, 0, 0);
      acc[0][t] =
          __builtin_amdgcn_mfma_f32_16x16x32_bf16(al0, Bh[s][t], acc[0][t], 0, 0, 0);
      acc[1][t] =
          __builtin_amdgcn_mfma_f32_16x16x32_bf16(ah1, Bh[s][t], acc[1][t], 0, 0, 0);
      acc[1][t] =
          __builtin_amdgcn_mfma_f32_16x16x32_bf16(ah1, Bl[s][t], acc[1][t], 0, 0, 0);
      acc[1][t] =
          __builtin_amdgcn_mfma_f32_16x16x32_bf16(al1, Bh[s][t], acc[1][t], 0, 0, 0);
    }
    if (r + 3 < 16) LOADB((r + 3) % 3, r + 3);  // B issue at round end
    asm volatile("" ::: "memory");              // pin issue position
  }
#undef LOADB

  // merge k-halves (reuse A-LDS; A fully consumed): kh=1 export, kh=0 absorb
  f32x4(*red)[64][6] = (f32x4(*)[64][6])lds;   // 24.5 KB < 128 KB
  __syncthreads();                             // all waves done reading A
  if (kh == 1) {
#pragma unroll
    for (int f = 0; f < 2; f++)
#pragma unroll
      for (int t = 0; t < 3; t++) red[nh][lane][f * 3 + t] = acc[f][t];
  }
  __syncthreads();
  if (kh == 1) return;
#pragma unroll
  for (int f = 0; f < 2; f++)
#pragma unroll
    for (int t = 0; t < 3; t++) acc[f][t] += red[nh][lane][f * 3 + t];

  // epilogue: bias + store + V column sums
  const int bb = rowBase >> 12;
#pragma unroll
  for (int f = 0; f < 2; f++)
#pragma unroll
    for (int t = 0; t < 3; t++) {
      int nt = nh * 3 + t;
      int n = nt * 16 + l16;
      int mat = n >> 6;
      int col = n & 63;
      float bias = (mat == 0) ? bq[col] : ((mat == 1) ? bk[col] : bv[col]);
      float* dst = qkv + (size_t)mat * MROWS * DDIM +
                   (size_t)(rowBase + f * 16 + quad * 4) * DDIM + col;
      float vs = 0.f;
#pragma unroll
      for (int rr = 0; rr < 4; rr++) {
        float val = acc[f][t][rr] + bias;
        dst[rr * DDIM] = val;
        vs += val;
      }
      if (nt >= 8) {                          // V tiles -> Vsum
        vs += __shfl_xor(vs, 16, 64);
        vs += __shfl_xor(vs, 32, 64);
        if (quad == 0) atomicAdd(&Vsum[bb * DDIM + (n - 128)], vs);
      }
    }
}

// ---------------------------------------------------------------------------
// Attention: 2 queries per wave, 32 lanes each, lane owns a float2 dim-pair.
// Full-row softmax collapses to: 5 window exps + (S - nvalid) background
// exp(0-m) terms; background numerator = Vsum - sum(window V).
// ---------------------------------------------------------------------------
__global__ __launch_bounds__(256) void attn_kernel(
    const float* __restrict__ qkv, const float* __restrict__ Vsum,
    float* __restrict__ out) {
  const float* Qf = qkv;
  const float* Kf = qkv + (size_t)MROWS * DDIM;
  const float* Vf = qkv + (size_t)2 * MROWS * DDIM;
  int l = threadIdx.x & 31;
  int qidx = blockIdx.x * 8 + (threadIdx.x >> 5);
  int b = qidx >> 12;
  int i = qidx & 4095;

  float2 q = *(const float2*)(const void*)(Qf + (size_t)qidx * DDIM + 2 * l);
  float sc[5];
  float2 vv[5];
  bool val[5];
#pragma unroll
  for (int w = 0; w < 5; w++) {
    int j = i + 2 * w - 4;                    // DIL*(w - WIN/2), DIL=2
    val[w] = (j >= 0) && (j < S_LEN);
    int jj = val[w] ? j : i;
    size_t off = (size_t)(b * S_LEN + jj) * DDIM + 2 * l;
    float2 kk = *(const float2*)(const void*)(Kf + off);
    vv[w] = *(const float2*)(const void*)(Vf + off);
    float p = q.x * kk.x + q.y * kk.y;
#pragma unroll
    for (int d = 1; d < 32; d <<= 1) p += __shfl_xor(p, d, 64);
    sc[w] = p;
  }

  float mx = 0.f;                             // background score 0 in the max
#pragma unroll
  for (int w = 0; w < 5; w++)
    if (val[w]) mx = fmaxf(mx, sc[w]);

  float denom = 0.f;
  float2 accv = {0.f, 0.f}, vsel = {0.f, 0.f};
  int nval = 0;
#pragma unroll
  for (int w = 0; w < 5; w++)
    if (val[w]) {
      float pexp = __expf(sc[w] - mx);
      denom += pexp;
      accv.x += pexp * vv[w].x;
      accv.y += pexp * vv[w].y;
      vsel.x += vv[w].x;
      vsel.y += vv[w].y;
      nval++;
    }
  float pbg = __expf(-mx);
  denom += pbg * (float)(S_LEN - nval);
  float2 vsm = *(const float2*)(const void*)(Vsum + b * DDIM + 2 * l);
  accv.x += pbg * (vsm.x - vsel.x);
  accv.y += pbg * (vsm.y - vsel.y);

  float2 o = {accv.x / denom, accv.y / denom};
  *(float2*)(void*)(out + (size_t)qidx * DDIM + 2 * l) = o;
}

// ---------------------------------------------------------------------------
extern "C" void kernel_launch(void* const* d_in, const int* in_sizes, int n_in,
                              void* d_out, int out_size, void* d_ws,
                              size_t ws_size, hipStream_t stream) {
  const float* x = (const float*)d_in[0];
  const float* Wq = (const float*)d_in[1];
  const float* bq = (const float*)d_in[2];
  const float* Wk = (const float*)d_in[3];
  const float* bk = (const float*)d_in[4];
  const float* Wv = (const float*)d_in[5];
  const float* bv = (const float*)d_in[6];
  float* out = (float*)d_out;

  char* ws = (char*)d_ws;
  bf16* Wt2_hi = (bf16*)ws;                   // 32*6144*2 = 393216 B
  bf16* Wt2_lo = (bf16*)(ws + 393216);        // 393216 B
  float* qkv = (float*)(ws + 786432);         // 3*8192*64*4 = 6291456 B
  float* Vsum = (float*)(ws + 786432 + 6291456);  // 512 B
  // total workspace ~7.1 MB

  hipLaunchKernelGGL(pack_w_kernel, dim3(48), dim3(256), 0, stream, Wq, Wk, Wv,
                     Wt2_hi, Wt2_lo, Vsum);
  hipLaunchKernelGGL(qkv_gemm_kernel, dim3(256), dim3(512), 0, stream, x,
                     Wt2_hi, Wt2_lo, bq, bk, bv, qkv, Vsum);
  hipLaunchKernelGGL(attn_kernel, dim3(1024), dim3(256), 0, stream, qkv, Vsum,
                     out);
}